// Round 2
// baseline (1234.833 us; speedup 1.0000x reference)
//
#include <hip/hip_runtime.h>
#include <stdint.h>

#define BB 128
#define TT 256
#define CC 384
#define HH 6
#define DD 64
#define FFF 1536
#define ROWS (BB*TT)   // 32768

// chunking to keep peak workspace ~142 MB (suspected ws_size limit caused R1 abort)
#define ABC 16                 // batches per attention chunk
#define NAC (BB/ABC)           // 8 attention chunks
#define FCH 8192               // rows per FFN chunk
#define NFC (ROWS/FCH)         // 4 FFN chunks

typedef unsigned short u16;
typedef __bf16 bf8v __attribute__((ext_vector_type(8)));
typedef float f4v __attribute__((ext_vector_type(4)));

__device__ __forceinline__ float bf2f(u16 u) {
    unsigned int v = ((unsigned int)u) << 16;
    float f;
    __builtin_memcpy(&f, &v, 4);
    return f;
}
__device__ __forceinline__ u16 f2bf(float f) {
    unsigned int u;
    __builtin_memcpy(&u, &f, 4);
    u += 0x7fffu + ((u >> 16) & 1u);   // RNE; inputs finite
    return (u16)(u >> 16);
}

// ---------------- LayerNorm: fp32 in -> bf16 out (1 wave per row of 384) ------
__global__ __launch_bounds__(256) void ln_kernel(
    const float* __restrict__ x, const float* __restrict__ g,
    const float* __restrict__ b, u16* __restrict__ out)
{
    const int row  = blockIdx.x * 4 + (threadIdx.x >> 6);
    const int lane = threadIdx.x & 63;
    const float* xr = x + (long long)row * CC;
    float v[6]; float s = 0.f;
#pragma unroll
    for (int i = 0; i < 6; ++i) { v[i] = xr[lane + i * 64]; s += v[i]; }
#pragma unroll
    for (int o = 32; o > 0; o >>= 1) s += __shfl_xor(s, o);
    const float mu = s * (1.f / CC);
    float q = 0.f;
#pragma unroll
    for (int i = 0; i < 6; ++i) { float d = v[i] - mu; q += d * d; }
#pragma unroll
    for (int o = 32; o > 0; o >>= 1) q += __shfl_xor(q, o);
    const float inv = rsqrtf(q * (1.f / CC) + 1e-5f);
    u16* orow = out + (long long)row * CC;
#pragma unroll
    for (int i = 0; i < 6; ++i) {
        int c = lane + i * 64;
        orow[c] = f2bf((v[i] - mu) * inv * g[c] + b[c]);
    }
}

// ---------------- Weight convert: fp32 -> bf16, transposed to (N x K) --------
__global__ __launch_bounds__(256) void cvt_weights(
    const float* __restrict__ Wq, const float* __restrict__ Wk, const float* __restrict__ Wv,
    const float* __restrict__ bq, const float* __restrict__ bk, const float* __restrict__ bv,
    const float* __restrict__ Wp, const float* __restrict__ W1, const float* __restrict__ W2,
    u16* __restrict__ wqkvT, u16* __restrict__ wpT, u16* __restrict__ w1T,
    u16* __restrict__ w2T, float* __restrict__ bqkv)
{
    const int S0 = 1152 * 384, S1 = 384 * 384, S2 = 1536 * 384, S3 = 384 * 1536;
    int i = blockIdx.x * 256 + threadIdx.x;
    if (i < S0) {
        int n = i / 384, k = i % 384;
        const float* W = (n < 384) ? Wq : (n < 768) ? Wk : Wv;
        int nn = (n >= 768) ? n - 768 : (n >= 384) ? n - 384 : n;
        int h = nn >> 6, d = nn & 63;
        wqkvT[i] = f2bf(W[h * (384 * 64) + k * 64 + d]);
        return;
    }
    i -= S0;
    if (i < S1) { int n = i / 384, k = i % 384; wpT[i] = f2bf(Wp[k * 384 + n]); return; }
    i -= S1;
    if (i < S2) { int n = i / 384, k = i % 384; w1T[i] = f2bf(W1[k * 1536 + n]); return; }
    i -= S2;
    if (i < S3) { int n = i / 1536, k = i % 1536; w2T[i] = f2bf(W2[k * 384 + n]); return; }
    i -= S3;
    if (i < 1152) bqkv[i] = (i < 384) ? bq[i] : (i < 768) ? bk[i - 384] : bv[i - 768];
}

// ---------------- V transpose: qkv (b,t,h,d) V-cols -> vt (b,h,d,t) ----------
__global__ __launch_bounds__(256) void vtrans_kernel(
    const u16* __restrict__ qkv, u16* __restrict__ vt)
{
    __shared__ u16 tile[64][65];
    const int z = blockIdx.x;          // b*H + h
    const int tb = blockIdx.y;         // t-block of 64
    const int zb = z / HH, zh = z % HH;
    const u16* src = qkv + ((long long)(zb * TT + tb * 64)) * 1152 + 768 + zh * 64;
    const int tid = threadIdx.x;
#pragma unroll
    for (int it = 0; it < 16; ++it) {
        int idx = it * 256 + tid; int tl = idx >> 6, d = idx & 63;
        tile[tl][d] = src[(long long)tl * 1152 + d];
    }
    __syncthreads();
    u16* dst = vt + (long long)z * 64 * 256 + tb * 64;
#pragma unroll
    for (int it = 0; it < 16; ++it) {
        int idx = it * 256 + tid; int d = idx >> 6, tl = idx & 63;
        dst[(long long)d * 256 + tl] = tile[tl][d];
    }
}

// ---------------- causal softmax over s (in-place, bf16), 1 wave per row -----
__global__ __launch_bounds__(256) void softmax_kernel(u16* __restrict__ sc)
{
    const long long row = (long long)blockIdx.x * 4 + (threadIdx.x >> 6);
    const int lane = threadIdx.x & 63;
    const int t = (int)(row & (TT - 1));
    u16* p = sc + row * TT;
    ushort4 u = *(const ushort4*)(p + lane * 4);
    const u16 raw[4] = { u.x, u.y, u.z, u.w };
    float v[4]; float m = -1e30f;
#pragma unroll
    for (int i = 0; i < 4; ++i) {
        int s = lane * 4 + i;
        v[i] = (s <= t) ? bf2f(raw[i]) : -1e30f;
        m = fmaxf(m, v[i]);
    }
#pragma unroll
    for (int o = 32; o > 0; o >>= 1) m = fmaxf(m, __shfl_xor(m, o));
    float sum = 0.f;
#pragma unroll
    for (int i = 0; i < 4; ++i) {
        int s = lane * 4 + i;
        float e = (s <= t) ? __expf(v[i] - m) : 0.f;
        v[i] = e; sum += e;
    }
#pragma unroll
    for (int o = 32; o > 0; o >>= 1) sum += __shfl_xor(sum, o);
    const float r = 1.f / sum;
    ushort4 w;
    w.x = f2bf(v[0] * r); w.y = f2bf(v[1] * r);
    w.z = f2bf(v[2] * r); w.w = f2bf(v[3] * r);
    *(ushort4*)(p + lane * 4) = w;
}

// ---------------- Generic bf16 MFMA GEMM: C = scale*(A @ B^T) [+bias][+res][relu]
template<int BM, int BN, bool OUTBF, bool RELU, bool HASRES>
__global__ __launch_bounds__(256) void gemm_bt(
    const u16* __restrict__ A, const u16* __restrict__ Bw, void* __restrict__ Cp,
    const float* __restrict__ bias, const float* __restrict__ res,
    int K, int lda, int ldb, int ldc,
    long long sAb, long long sAh, long long sBb, long long sBh,
    long long sCb, long long sCh, int Hb, float scale)
{
    __shared__ __align__(16) u16 As[BM * 32];
    __shared__ __align__(16) u16 Bs[BN * 32];

    const int tid = threadIdx.x;
    const int wave = tid >> 6, lane = tid & 63;
    const int quad = lane >> 4, lq = lane & 15;

    const int z = blockIdx.z;
    const int zb = z / Hb, zh = z % Hb;
    const int m0 = blockIdx.x * BM;
    const int n0 = blockIdx.y * BN;

    A  += (long long)zb * sAb + (long long)zh * sAh + (long long)m0 * lda;
    Bw += (long long)zb * sBb + (long long)zh * sBh + (long long)n0 * ldb;
    const long long coff = (long long)zb * sCb + (long long)zh * sCh;

    constexpr int WM = BM / 2, WN = BN / 2;
    constexpr int MT = WM / 16, NT = WN / 16;
    const int wm0 = (wave >> 1) * WM;
    const int wn0 = (wave & 1) * WN;

    f4v acc[MT][NT];
#pragma unroll
    for (int i = 0; i < MT; ++i)
#pragma unroll
        for (int j = 0; j < NT; ++j) acc[i][j] = (f4v){0.f, 0.f, 0.f, 0.f};

    constexpr int AIT = BM * 4 / 256;
    constexpr int BIT = BN * 4 / 256;

    for (int k0 = 0; k0 < K; k0 += 32) {
        uint4 atmp[AIT], btmp[BIT];
#pragma unroll
        for (int j = 0; j < AIT; ++j) {
            int idx = j * 256 + tid; int r = idx >> 2, c = idx & 3;
            atmp[j] = *(const uint4*)(A + (long long)r * lda + k0 + c * 8);
        }
#pragma unroll
        for (int j = 0; j < BIT; ++j) {
            int idx = j * 256 + tid; int r = idx >> 2, c = idx & 3;
            btmp[j] = *(const uint4*)(Bw + (long long)r * ldb + k0 + c * 8);
        }
        __syncthreads();   // previous iteration's LDS reads complete
#pragma unroll
        for (int j = 0; j < AIT; ++j) { int idx = j * 256 + tid; *(uint4*)(As + idx * 8) = atmp[j]; }
#pragma unroll
        for (int j = 0; j < BIT; ++j) { int idx = j * 256 + tid; *(uint4*)(Bs + idx * 8) = btmp[j]; }
        __syncthreads();

        bf8v af[MT], bfr[NT];
#pragma unroll
        for (int i = 0; i < MT; ++i)
            af[i] = *(const bf8v*)(As + (wm0 + i * 16 + lq) * 32 + quad * 8);
#pragma unroll
        for (int j = 0; j < NT; ++j)
            bfr[j] = *(const bf8v*)(Bs + (wn0 + j * 16 + lq) * 32 + quad * 8);
#pragma unroll
        for (int i = 0; i < MT; ++i)
#pragma unroll
            for (int j = 0; j < NT; ++j)
                acc[i][j] = __builtin_amdgcn_mfma_f32_16x16x32_bf16(af[i], bfr[j], acc[i][j], 0, 0, 0);
    }

    // epilogue: D[row=quad*4+r][col=lq] per 16x16 tile
#pragma unroll
    for (int i = 0; i < MT; ++i) {
#pragma unroll
        for (int j = 0; j < NT; ++j) {
            const int gcol = n0 + wn0 + j * 16 + lq;
            const float bcol = bias ? bias[gcol] : 0.f;
#pragma unroll
            for (int r = 0; r < 4; ++r) {
                const int grow = m0 + wm0 + i * 16 + quad * 4 + r;
                const long long off = coff + (long long)grow * ldc + gcol;
                float v = acc[i][j][r] * scale + bcol;
                if (HASRES) v += res[off];
                if (RELU)   v = fmaxf(v, 0.f);
                if (OUTBF)  ((u16*)Cp)[off] = f2bf(v);
                else        ((float*)Cp)[off] = v;
            }
        }
    }
}

extern "C" void kernel_launch(void* const* d_in, const int* in_sizes, int n_in,
                              void* d_out, int out_size, void* d_ws, size_t ws_size,
                              hipStream_t stream)
{
    const float* x    = (const float*)d_in[0];
    const float* ln1g = (const float*)d_in[1];
    const float* ln1b = (const float*)d_in[2];
    const float* Wk   = (const float*)d_in[3];
    const float* bk   = (const float*)d_in[4];
    const float* Wq   = (const float*)d_in[5];
    const float* bq   = (const float*)d_in[6];
    const float* Wv   = (const float*)d_in[7];
    const float* bv   = (const float*)d_in[8];
    const float* Wp   = (const float*)d_in[9];
    const float* bp   = (const float*)d_in[10];
    const float* ln2g = (const float*)d_in[11];
    const float* ln2b = (const float*)d_in[12];
    const float* W1   = (const float*)d_in[13];
    const float* b1   = (const float*)d_in[14];
    const float* W2   = (const float*)d_in[15];
    const float* b2   = (const float*)d_in[16];

    // ---- workspace carve-up: peak ~142 MB ----
    char* ws = (char*)d_ws;
    size_t off = 0;
    auto alloc = [&](size_t bytes) -> char* {
        char* p = ws + off; off += (bytes + 255) & ~(size_t)255; return p;
    };
    u16*   wqkvT = (u16*)alloc((size_t)1152 * 384 * 2);
    u16*   wpT   = (u16*)alloc((size_t)384 * 384 * 2);
    u16*   w1T   = (u16*)alloc((size_t)1536 * 384 * 2);
    u16*   w2T   = (u16*)alloc((size_t)384 * 1536 * 2);
    float* bqkv  = (float*)alloc((size_t)1152 * 4);
    u16*   h     = (u16*)alloc((size_t)ROWS * CC * 2);             // LN1 out; reused: attnout, h2
    u16*   qkv   = (u16*)alloc((size_t)ROWS * 1152 * 2);           // Q|K|V; reused: x1 (fp32)
    u16*   vt    = (u16*)alloc((size_t)BB * HH * DD * TT * 2);     // V^T; reused: ff (start)
    u16*   sc    = (u16*)alloc((size_t)ABC * HH * TT * TT * 2);    // per-chunk scores
    u16* attnout = h;
    u16* h2      = h;
    float* x1    = (float*)qkv;   // 50.3 MB inside dead 75.5 MB qkv region
    u16*   ff    = vt;            // 25.2 MB chunk inside dead vt+sc region (37.8 MB)

    const float scs = 0.05103103630798287f;  // 384^-0.5 (faithful quirk)

    // 1) LN1
    ln_kernel<<<ROWS / 4, 256, 0, stream>>>(x, ln1g, ln1b, h);
    // 2) weight convert/transpose/pack
    cvt_weights<<<6918, 256, 0, stream>>>(Wq, Wk, Wv, bq, bk, bv, Wp, W1, W2,
                                          wqkvT, wpT, w1T, w2T, bqkv);
    // 3) QKV
    gemm_bt<128, 128, true, false, false><<<dim3(ROWS / 128, 1152 / 128, 1), 256, 0, stream>>>(
        h, wqkvT, qkv, bqkv, nullptr, 384, 384, 384, 1152,
        0, 0, 0, 0, 0, 0, 1, 1.f);
    // 4) V transpose (all batches)
    vtrans_kernel<<<dim3(BB * HH, 4), 256, 0, stream>>>(qkv, vt);
    // 5-7) attention, chunked over batches
    for (int bc = 0; bc < NAC; ++bc) {
        const long long qo = (long long)bc * ABC * TT * 1152;
        // scores = K @ Q^T * C^-0.5
        gemm_bt<128, 128, true, false, false><<<dim3(2, 2, ABC * HH), 256, 0, stream>>>(
            qkv + 384 + qo, qkv + qo, sc, nullptr, nullptr, 64, 1152, 1152, TT,
            (long long)TT * 1152, 64, (long long)TT * 1152, 64,
            (long long)HH * TT * TT, (long long)TT * TT, HH, scs);
        // causal softmax
        softmax_kernel<<<(ABC * HH * TT) / 4, 256, 0, stream>>>(sc);
        // out = attn @ V
        gemm_bt<128, 64, true, false, false><<<dim3(2, 1, ABC * HH), 256, 0, stream>>>(
            sc, vt + (long long)bc * ABC * HH * DD * TT,
            attnout + (long long)bc * ABC * TT * CC, nullptr, nullptr, TT, TT, TT, CC,
            (long long)HH * TT * TT, (long long)TT * TT,
            (long long)HH * DD * TT, (long long)DD * TT,
            (long long)TT * CC, 64, HH, 1.f);
    }
    // 8) x1 = x + attnout @ Wp + bp   (x1 aliases dead qkv)
    gemm_bt<128, 128, false, false, true><<<dim3(ROWS / 128, CC / 128, 1), 256, 0, stream>>>(
        attnout, wpT, x1, bp, x, CC, CC, CC, CC,
        0, 0, 0, 0, 0, 0, 1, 1.f);
    // 9) LN2
    ln_kernel<<<ROWS / 4, 256, 0, stream>>>(x1, ln2g, ln2b, h2);
    // 10-11) FFN, chunked over rows (ff aliases dead vt+sc)
    for (int fc = 0; fc < NFC; ++fc) {
        const long long ro = (long long)fc * FCH;
        gemm_bt<128, 128, true, true, false><<<dim3(FCH / 128, FFF / 128, 1), 256, 0, stream>>>(
            h2 + ro * CC, w1T, ff, b1, nullptr, CC, CC, CC, FFF,
            0, 0, 0, 0, 0, 0, 1, 1.f);
        gemm_bt<128, 128, false, false, true><<<dim3(FCH / 128, CC / 128, 1), 256, 0, stream>>>(
            ff, w2T, (float*)d_out + ro * CC, b2, x1 + ro * CC, FFF, FFF, FFF, CC,
            0, 0, 0, 0, 0, 0, 1, 1.f);
    }
}

// Round 3
// 547.655 us; speedup vs baseline: 2.2548x; 2.2548x over previous
//
#include <hip/hip_runtime.h>
#include <stdint.h>

#define BB 128
#define TT 256
#define CC 384
#define HH 6
#define DD 64
#define FFF 1536
#define ROWS (BB*TT)   // 32768

// chunking keeps peak workspace ~154.5 MB (R2 proved >=142 MB works; R1 failed at 282)
#define ABC 32                 // batches per attention chunk
#define NAC (BB/ABC)           // 4 attention chunks
#define FCH 16384              // rows per FFN chunk
#define NFC (ROWS/FCH)         // 2 FFN chunks

typedef unsigned short u16;
typedef __bf16 bf8v __attribute__((ext_vector_type(8)));
typedef float f4v __attribute__((ext_vector_type(4)));

__device__ __forceinline__ float bf2f(u16 u) {
    unsigned int v = ((unsigned int)u) << 16;
    float f;
    __builtin_memcpy(&f, &v, 4);
    return f;
}
__device__ __forceinline__ u16 f2bf(float f) {
    unsigned int u;
    __builtin_memcpy(&u, &f, 4);
    u += 0x7fffu + ((u >> 16) & 1u);   // RNE; inputs finite
    return (u16)(u >> 16);
}

// async global->LDS 16B per lane; LDS dest must be wave-uniform base + lane*16
__device__ __forceinline__ void gload_lds16(const void* g, void* l) {
    __builtin_amdgcn_global_load_lds(
        (__attribute__((address_space(1))) void*)(g),
        (__attribute__((address_space(3))) void*)(l), 16, 0, 0);
}

// ---------------- LayerNorm: fp32 in -> bf16 out (1 wave per row of 384) ------
__global__ __launch_bounds__(256) void ln_kernel(
    const float* __restrict__ x, const float* __restrict__ g,
    const float* __restrict__ b, u16* __restrict__ out)
{
    const int row  = blockIdx.x * 4 + (threadIdx.x >> 6);
    const int lane = threadIdx.x & 63;
    const float* xr = x + (long long)row * CC;
    float v[6]; float s = 0.f;
#pragma unroll
    for (int i = 0; i < 6; ++i) { v[i] = xr[lane + i * 64]; s += v[i]; }
#pragma unroll
    for (int o = 32; o > 0; o >>= 1) s += __shfl_xor(s, o);
    const float mu = s * (1.f / CC);
    float q = 0.f;
#pragma unroll
    for (int i = 0; i < 6; ++i) { float d = v[i] - mu; q += d * d; }
#pragma unroll
    for (int o = 32; o > 0; o >>= 1) q += __shfl_xor(q, o);
    const float inv = rsqrtf(q * (1.f / CC) + 1e-5f);
    u16* orow = out + (long long)row * CC;
#pragma unroll
    for (int i = 0; i < 6; ++i) {
        int c = lane + i * 64;
        orow[c] = f2bf((v[i] - mu) * inv * g[c] + b[c]);
    }
}

// ---------------- Weight convert: fp32 -> bf16, transposed to (N x K) --------
__global__ __launch_bounds__(256) void cvt_weights(
    const float* __restrict__ Wq, const float* __restrict__ Wk, const float* __restrict__ Wv,
    const float* __restrict__ bq, const float* __restrict__ bk, const float* __restrict__ bv,
    const float* __restrict__ Wp, const float* __restrict__ W1, const float* __restrict__ W2,
    u16* __restrict__ wqkvT, u16* __restrict__ wpT, u16* __restrict__ w1T,
    u16* __restrict__ w2T, float* __restrict__ bqkv)
{
    const int S0 = 1152 * 384, S1 = 384 * 384, S2 = 1536 * 384, S3 = 384 * 1536;
    int i = blockIdx.x * 256 + threadIdx.x;
    if (i < S0) {
        int n = i / 384, k = i % 384;
        const float* W = (n < 384) ? Wq : (n < 768) ? Wk : Wv;
        int nn = (n >= 768) ? n - 768 : (n >= 384) ? n - 384 : n;
        int h = nn >> 6, d = nn & 63;
        wqkvT[i] = f2bf(W[h * (384 * 64) + k * 64 + d]);
        return;
    }
    i -= S0;
    if (i < S1) { int n = i / 384, k = i % 384; wpT[i] = f2bf(Wp[k * 384 + n]); return; }
    i -= S1;
    if (i < S2) { int n = i / 384, k = i % 384; w1T[i] = f2bf(W1[k * 1536 + n]); return; }
    i -= S2;
    if (i < S3) { int n = i / 1536, k = i % 1536; w2T[i] = f2bf(W2[k * 384 + n]); return; }
    i -= S3;
    if (i < 1152) bqkv[i] = (i < 384) ? bq[i] : (i < 768) ? bk[i - 384] : bv[i - 768];
}

// ---------------- V transpose: qkv (b,t,h,d) V-cols -> vt (b,h,d,t) ----------
__global__ __launch_bounds__(256) void vtrans_kernel(
    const u16* __restrict__ qkv, u16* __restrict__ vt)
{
    __shared__ u16 tile[64][65];
    const int z = blockIdx.x;          // b*H + h
    const int tb = blockIdx.y;         // t-block of 64
    const int zb = z / HH, zh = z % HH;
    const u16* src = qkv + ((long long)(zb * TT + tb * 64)) * 1152 + 768 + zh * 64;
    const int tid = threadIdx.x;
#pragma unroll
    for (int it = 0; it < 16; ++it) {
        int idx = it * 256 + tid; int tl = idx >> 6, d = idx & 63;
        tile[tl][d] = src[(long long)tl * 1152 + d];
    }
    __syncthreads();
    u16* dst = vt + (long long)z * 64 * 256 + tb * 64;
#pragma unroll
    for (int it = 0; it < 16; ++it) {
        int idx = it * 256 + tid; int d = idx >> 6, tl = idx & 63;
        dst[(long long)d * 256 + tl] = tile[tl][d];
    }
}

// ---------------- causal softmax over s (in-place, bf16), 1 wave per row -----
__global__ __launch_bounds__(256) void softmax_kernel(u16* __restrict__ sc)
{
    const long long row = (long long)blockIdx.x * 4 + (threadIdx.x >> 6);
    const int lane = threadIdx.x & 63;
    const int t = (int)(row & (TT - 1));
    u16* p = sc + row * TT;
    ushort4 u = *(const ushort4*)(p + lane * 4);
    const u16 raw[4] = { u.x, u.y, u.z, u.w };
    float v[4]; float m = -1e30f;
#pragma unroll
    for (int i = 0; i < 4; ++i) {
        int s = lane * 4 + i;
        v[i] = (s <= t) ? bf2f(raw[i]) : -1e30f;
        m = fmaxf(m, v[i]);
    }
#pragma unroll
    for (int o = 32; o > 0; o >>= 1) m = fmaxf(m, __shfl_xor(m, o));
    float sum = 0.f;
#pragma unroll
    for (int i = 0; i < 4; ++i) {
        int s = lane * 4 + i;
        float e = (s <= t) ? __expf(v[i] - m) : 0.f;
        v[i] = e; sum += e;
    }
#pragma unroll
    for (int o = 32; o > 0; o >>= 1) sum += __shfl_xor(sum, o);
    const float r = 1.f / sum;
    ushort4 w;
    w.x = f2bf(v[0] * r); w.y = f2bf(v[1] * r);
    w.z = f2bf(v[2] * r); w.w = f2bf(v[3] * r);
    *(ushort4*)(p + lane * 4) = w;
}

// ---------------- Generic bf16 MFMA GEMM: C = scale*(A @ B^T) [+bias][+res][relu]
// m97 structure: 128-wide tiles, BK=32, global_load_lds width-16 staging, 2 barriers/iter.
// LDS layout is deliberately UNPADDED: global_load_lds requires dest = wave-uniform
// base + lane*16 (m104 caveat); m97 hit 874 TF with this exact layout.
template<int BM, int BN, bool OUTBF, bool RELU, bool HASRES>
__global__ __launch_bounds__(256) void gemm_bt(
    const u16* __restrict__ A, const u16* __restrict__ Bw, void* __restrict__ Cp,
    const float* __restrict__ bias, const float* __restrict__ res,
    int K, int lda, int ldb, int ldc,
    long long sAb, long long sAh, long long sBb, long long sBh,
    long long sCb, long long sCh, int Hb, float scale)
{
    __shared__ __align__(16) u16 As[BM * 32];
    __shared__ __align__(16) u16 Bs[BN * 32];

    const int tid = threadIdx.x;
    const int wave = tid >> 6, lane = tid & 63;
    const int quad = lane >> 4, lq = lane & 15;

    const int z = blockIdx.z;
    const int zb = z / Hb, zh = z % Hb;
    const int m0 = blockIdx.x * BM;
    const int n0 = blockIdx.y * BN;

    A  += (long long)zb * sAb + (long long)zh * sAh + (long long)m0 * lda;
    Bw += (long long)zb * sBb + (long long)zh * sBh + (long long)n0 * ldb;
    const long long coff = (long long)zb * sCb + (long long)zh * sCh;

    constexpr int WM = BM / 2, WN = BN / 2;
    constexpr int MT = WM / 16, NT = WN / 16;
    const int wm0 = (wave >> 1) * WM;
    const int wn0 = (wave & 1) * WN;

    f4v acc[MT][NT];
#pragma unroll
    for (int i = 0; i < MT; ++i)
#pragma unroll
        for (int j = 0; j < NT; ++j) acc[i][j] = (f4v){0.f, 0.f, 0.f, 0.f};

    constexpr int AIT = BM / 64;   // 16B chunks per thread for A tile
    constexpr int BIT = BN / 64;

    for (int k0 = 0; k0 < K; k0 += 32) {
        __syncthreads();   // previous iteration's LDS reads complete before overwrite
#pragma unroll
        for (int j = 0; j < AIT; ++j) {
            int idx = j * 256 + tid; int r = idx >> 2, c = idx & 3;
            gload_lds16(A + (long long)r * lda + k0 + c * 8, As + idx * 8);
        }
#pragma unroll
        for (int j = 0; j < BIT; ++j) {
            int idx = j * 256 + tid; int r = idx >> 2, c = idx & 3;
            gload_lds16(Bw + (long long)r * ldb + k0 + c * 8, Bs + idx * 8);
        }
        __syncthreads();   // compiler emits vmcnt(0) drain before s_barrier

        bf8v af[MT], bfr[NT];
#pragma unroll
        for (int i = 0; i < MT; ++i)
            af[i] = *(const bf8v*)(As + (wm0 + i * 16 + lq) * 32 + quad * 8);
#pragma unroll
        for (int j = 0; j < NT; ++j)
            bfr[j] = *(const bf8v*)(Bs + (wn0 + j * 16 + lq) * 32 + quad * 8);
#pragma unroll
        for (int i = 0; i < MT; ++i)
#pragma unroll
            for (int j = 0; j < NT; ++j)
                acc[i][j] = __builtin_amdgcn_mfma_f32_16x16x32_bf16(af[i], bfr[j], acc[i][j], 0, 0, 0);
    }

    // epilogue: D[row=quad*4+r][col=lq] per 16x16 tile
#pragma unroll
    for (int i = 0; i < MT; ++i) {
#pragma unroll
        for (int j = 0; j < NT; ++j) {
            const int gcol = n0 + wn0 + j * 16 + lq;
            const float bcol = bias ? bias[gcol] : 0.f;
#pragma unroll
            for (int r = 0; r < 4; ++r) {
                const int grow = m0 + wm0 + i * 16 + quad * 4 + r;
                const long long off = coff + (long long)grow * ldc + gcol;
                float v = acc[i][j][r] * scale + bcol;
                if (HASRES) v += res[off];
                if (RELU)   v = fmaxf(v, 0.f);
                if (OUTBF)  ((u16*)Cp)[off] = f2bf(v);
                else        ((float*)Cp)[off] = v;
            }
        }
    }
}

extern "C" void kernel_launch(void* const* d_in, const int* in_sizes, int n_in,
                              void* d_out, int out_size, void* d_ws, size_t ws_size,
                              hipStream_t stream)
{
    const float* x    = (const float*)d_in[0];
    const float* ln1g = (const float*)d_in[1];
    const float* ln1b = (const float*)d_in[2];
    const float* Wk   = (const float*)d_in[3];
    const float* bk   = (const float*)d_in[4];
    const float* Wq   = (const float*)d_in[5];
    const float* bq   = (const float*)d_in[6];
    const float* Wv   = (const float*)d_in[7];
    const float* bv   = (const float*)d_in[8];
    const float* Wp   = (const float*)d_in[9];
    const float* bp   = (const float*)d_in[10];
    const float* ln2g = (const float*)d_in[11];
    const float* ln2b = (const float*)d_in[12];
    const float* W1   = (const float*)d_in[13];
    const float* b1   = (const float*)d_in[14];
    const float* W2   = (const float*)d_in[15];
    const float* b2   = (const float*)d_in[16];

    // ---- workspace carve-up: peak ~154.5 MB ----
    char* ws = (char*)d_ws;
    size_t off = 0;
    auto alloc = [&](size_t bytes) -> char* {
        char* p = ws + off; off += (bytes + 255) & ~(size_t)255; return p;
    };
    u16*   wqkvT = (u16*)alloc((size_t)1152 * 384 * 2);
    u16*   wpT   = (u16*)alloc((size_t)384 * 384 * 2);
    u16*   w1T   = (u16*)alloc((size_t)1536 * 384 * 2);
    u16*   w2T   = (u16*)alloc((size_t)384 * 1536 * 2);
    float* bqkv  = (float*)alloc((size_t)1152 * 4);
    u16*   h     = (u16*)alloc((size_t)ROWS * CC * 2);             // LN1 out; reused: attnout, h2
    u16*   qkv   = (u16*)alloc((size_t)ROWS * 1152 * 2);           // Q|K|V; reused: x1 (fp32)
    u16*   vt    = (u16*)alloc((size_t)BB * HH * DD * TT * 2);     // V^T; reused: ff (start)
    u16*   sc    = (u16*)alloc((size_t)ABC * HH * TT * TT * 2);    // per-chunk scores; reused: ff (end)
    u16* attnout = h;
    u16* h2      = h;
    float* x1    = (float*)qkv;   // 50.3 MB inside dead 75.5 MB qkv region
    u16*   ff    = vt;            // 50.3 MB chunk exactly fills dead vt+sc region

    const float scs = 0.05103103630798287f;  // 384^-0.5 (faithful quirk)

    // 1) LN1
    ln_kernel<<<ROWS / 4, 256, 0, stream>>>(x, ln1g, ln1b, h);
    // 2) weight convert/transpose/pack
    cvt_weights<<<6918, 256, 0, stream>>>(Wq, Wk, Wv, bq, bk, bv, Wp, W1, W2,
                                          wqkvT, wpT, w1T, w2T, bqkv);
    // 3) QKV
    gemm_bt<128, 128, true, false, false><<<dim3(ROWS / 128, 1152 / 128, 1), 256, 0, stream>>>(
        h, wqkvT, qkv, bqkv, nullptr, 384, 384, 384, 1152,
        0, 0, 0, 0, 0, 0, 1, 1.f);
    // 4) V transpose (all batches)
    vtrans_kernel<<<dim3(BB * HH, 4), 256, 0, stream>>>(qkv, vt);
    // 5-7) attention, chunked over batches
    for (int bc = 0; bc < NAC; ++bc) {
        const long long qo = (long long)bc * ABC * TT * 1152;
        // scores = K @ Q^T * C^-0.5
        gemm_bt<128, 128, true, false, false><<<dim3(2, 2, ABC * HH), 256, 0, stream>>>(
            qkv + 384 + qo, qkv + qo, sc, nullptr, nullptr, 64, 1152, 1152, TT,
            (long long)TT * 1152, 64, (long long)TT * 1152, 64,
            (long long)HH * TT * TT, (long long)TT * TT, HH, scs);
        // causal softmax
        softmax_kernel<<<(ABC * HH * TT) / 4, 256, 0, stream>>>(sc);
        // out = attn @ V
        gemm_bt<128, 64, true, false, false><<<dim3(2, 1, ABC * HH), 256, 0, stream>>>(
            sc, vt + (long long)bc * ABC * HH * DD * TT,
            attnout + (long long)bc * ABC * TT * CC, nullptr, nullptr, TT, TT, TT, CC,
            (long long)HH * TT * TT, (long long)TT * TT,
            (long long)HH * DD * TT, (long long)DD * TT,
            (long long)TT * CC, 64, HH, 1.f);
    }
    // 8) x1 = x + attnout @ Wp + bp   (x1 aliases dead qkv)
    gemm_bt<128, 128, false, false, true><<<dim3(ROWS / 128, CC / 128, 1), 256, 0, stream>>>(
        attnout, wpT, x1, bp, x, CC, CC, CC, CC,
        0, 0, 0, 0, 0, 0, 1, 1.f);
    // 9) LN2
    ln_kernel<<<ROWS / 4, 256, 0, stream>>>(x1, ln2g, ln2b, h2);
    // 10-11) FFN, chunked over rows (ff aliases dead vt+sc)
    for (int fc = 0; fc < NFC; ++fc) {
        const long long ro = (long long)fc * FCH;
        gemm_bt<128, 128, true, true, false><<<dim3(FCH / 128, FFF / 128, 1), 256, 0, stream>>>(
            h2 + ro * CC, w1T, ff, b1, nullptr, CC, CC, CC, FFF,
            0, 0, 0, 0, 0, 0, 1, 1.f);
        gemm_bt<128, 128, false, false, true><<<dim3(FCH / 128, CC / 128, 1), 256, 0, stream>>>(
            ff, w2T, (float*)d_out + ro * CC, b2, x1 + ro * CC, FFF, FFF, FFF, CC,
            0, 0, 0, 0, 0, 0, 1, 1.f);
    }
}

// Round 4
// 449.593 us; speedup vs baseline: 2.7466x; 1.2181x over previous
//
#include <hip/hip_runtime.h>
#include <stdint.h>

#define BB 128
#define TT 256
#define CC 384
#define HH 6
#define DD 64
#define FFF 1536
#define ROWS (BB*TT)   // 32768

// FFN chunking keeps peak workspace ~154.5 MB (R3-proven size)
#define FCH 16384              // rows per FFN chunk
#define NFC (ROWS/FCH)         // 2 FFN chunks

typedef unsigned short u16;
typedef __bf16 bf8v __attribute__((ext_vector_type(8)));
typedef float f4v __attribute__((ext_vector_type(4)));

__device__ __forceinline__ float bf2f(u16 u) {
    unsigned int v = ((unsigned int)u) << 16;
    float f;
    __builtin_memcpy(&f, &v, 4);
    return f;
}
__device__ __forceinline__ u16 f2bf(float f) {
    unsigned int u;
    __builtin_memcpy(&u, &f, 4);
    u += 0x7fffu + ((u >> 16) & 1u);   // RNE; inputs finite
    return (u16)(u >> 16);
}

// async global->LDS 16B per lane; LDS dest must be wave-uniform base + lane*16
__device__ __forceinline__ void gload_lds16(const void* g, void* l) {
    __builtin_amdgcn_global_load_lds(
        (__attribute__((address_space(1))) void*)(g),
        (__attribute__((address_space(3))) void*)(l), 16, 0, 0);
}

// ---------------- LayerNorm: fp32 in -> bf16 out (1 wave per row of 384) ------
__global__ __launch_bounds__(256) void ln_kernel(
    const float* __restrict__ x, const float* __restrict__ g,
    const float* __restrict__ b, u16* __restrict__ out)
{
    const int row  = blockIdx.x * 4 + (threadIdx.x >> 6);
    const int lane = threadIdx.x & 63;
    const float* xr = x + (long long)row * CC;
    float v[6]; float s = 0.f;
#pragma unroll
    for (int i = 0; i < 6; ++i) { v[i] = xr[lane + i * 64]; s += v[i]; }
#pragma unroll
    for (int o = 32; o > 0; o >>= 1) s += __shfl_xor(s, o);
    const float mu = s * (1.f / CC);
    float q = 0.f;
#pragma unroll
    for (int i = 0; i < 6; ++i) { float d = v[i] - mu; q += d * d; }
#pragma unroll
    for (int o = 32; o > 0; o >>= 1) q += __shfl_xor(q, o);
    const float inv = rsqrtf(q * (1.f / CC) + 1e-5f);
    u16* orow = out + (long long)row * CC;
#pragma unroll
    for (int i = 0; i < 6; ++i) {
        int c = lane + i * 64;
        orow[c] = f2bf((v[i] - mu) * inv * g[c] + b[c]);
    }
}

// ---------------- Weight convert: fp32 -> bf16, transposed to (N x K) --------
__global__ __launch_bounds__(256) void cvt_weights(
    const float* __restrict__ Wq, const float* __restrict__ Wk, const float* __restrict__ Wv,
    const float* __restrict__ bq, const float* __restrict__ bk, const float* __restrict__ bv,
    const float* __restrict__ Wp, const float* __restrict__ W1, const float* __restrict__ W2,
    u16* __restrict__ wqkvT, u16* __restrict__ wpT, u16* __restrict__ w1T,
    u16* __restrict__ w2T, float* __restrict__ bqkv)
{
    const int S0 = 1152 * 384, S1 = 384 * 384, S2 = 1536 * 384, S3 = 384 * 1536;
    int i = blockIdx.x * 256 + threadIdx.x;
    if (i < S0) {
        int n = i / 384, k = i % 384;
        const float* W = (n < 384) ? Wq : (n < 768) ? Wk : Wv;
        int nn = (n >= 768) ? n - 768 : (n >= 384) ? n - 384 : n;
        int h = nn >> 6, d = nn & 63;
        wqkvT[i] = f2bf(W[h * (384 * 64) + k * 64 + d]);
        return;
    }
    i -= S0;
    if (i < S1) { int n = i / 384, k = i % 384; wpT[i] = f2bf(Wp[k * 384 + n]); return; }
    i -= S1;
    if (i < S2) { int n = i / 384, k = i % 384; w1T[i] = f2bf(W1[k * 1536 + n]); return; }
    i -= S2;
    if (i < S3) { int n = i / 1536, k = i % 1536; w2T[i] = f2bf(W2[k * 384 + n]); return; }
    i -= S3;
    if (i < 1152) bqkv[i] = (i < 384) ? bq[i] : (i < 768) ? bk[i - 384] : bv[i - 768];
}

// ---------------- V transpose: qkv (b,t,h,d) V-cols -> vt (b,h,d,t) ----------
__global__ __launch_bounds__(256) void vtrans_kernel(
    const u16* __restrict__ qkv, u16* __restrict__ vt)
{
    __shared__ u16 tile[64][65];
    const int z = blockIdx.x;          // b*H + h
    const int tb = blockIdx.y;         // t-block of 64
    const int zb = z / HH, zh = z % HH;
    const u16* src = qkv + ((long long)(zb * TT + tb * 64)) * 1152 + 768 + zh * 64;
    const int tid = threadIdx.x;
#pragma unroll
    for (int it = 0; it < 16; ++it) {
        int idx = it * 256 + tid; int tl = idx >> 6, d = idx & 63;
        tile[tl][d] = src[(long long)tl * 1152 + d];
    }
    __syncthreads();
    u16* dst = vt + (long long)z * 64 * 256 + tb * 64;
#pragma unroll
    for (int it = 0; it < 16; ++it) {
        int idx = it * 256 + tid; int d = idx >> 6, tl = idx & 63;
        dst[(long long)d * 256 + tl] = tile[tl][d];
    }
}

// ---------------- Fused flash-style causal attention --------------------------
// scores = K @ Q^T * C^-0.5 (faithful quirk), causal keeps s<=t, out = P @ V.
// Block = (b,h) x t-half(128 rows). 4 waves, each owns a 32-row t-strip.
// K/Q fragments straight from global (each head stripe = one 128B cacheline).
// P goes C-layout -> A-layout via per-wave-private LDS strip; NO barriers.
__global__ __launch_bounds__(256) void flash_kernel(
    const u16* __restrict__ qkv, const u16* __restrict__ vt, u16* __restrict__ attnout)
{
    __shared__ __align__(16) u16 Pl[128 * 72];   // stride 72: rows 16B-aligned, conflict-light

    const int bh = blockIdx.x;        // b*HH + h
    const int half = blockIdx.y;      // t rows [half*128, half*128+128)
    const int b = bh / HH, hh = bh % HH;
    const int tid = threadIdx.x;
    const int wave = tid >> 6, lane = tid & 63;
    const int quad = lane >> 4, lq = lane & 15;
    const int t0 = half * 128;

    const long long qrow = (long long)b * TT * 1152;
    const u16* Kb  = qkv + qrow + 384 + hh * 64;   // K segment cols
    const u16* Qb  = qkv + qrow + hh * 64;         // Q segment cols
    const u16* Vtb = vt + (long long)bh * (DD * TT);

    // A-frags (K rows of this wave's strip), loaded once: A[m=lq][k=quad*8+j]
    bf8v af[2][2];
#pragma unroll
    for (int i = 0; i < 2; ++i)
#pragma unroll
        for (int ks = 0; ks < 2; ++ks)
            af[i][ks] = *(const bf8v*)(Kb + (long long)(t0 + wave * 32 + i * 16 + lq) * 1152
                                          + ks * 32 + quad * 8);

    float m_run[2][4], l_run[2][4];
    f4v oacc[2][4];
#pragma unroll
    for (int i = 0; i < 2; ++i) {
#pragma unroll
        for (int r = 0; r < 4; ++r) { m_run[i][r] = -1e30f; l_run[i][r] = 0.f; }
#pragma unroll
        for (int j = 0; j < 4; ++j) oacc[i][j] = (f4v){0.f, 0.f, 0.f, 0.f};
    }

    const float scs = 0.05103103630798287f;  // 384^-0.5
    const int ntiles = 2 * (half + 1);       // causal skip: half0 -> 2 tiles, half1 -> 4
    for (int st = 0; st < ntiles; ++st) {
        const int s0 = st * 64;
        // ---- S-tile: 32 rows x 64 s, K=64 ----
        f4v sacc[2][4];
#pragma unroll
        for (int i = 0; i < 2; ++i)
#pragma unroll
            for (int j = 0; j < 4; ++j) sacc[i][j] = (f4v){0.f, 0.f, 0.f, 0.f};
#pragma unroll
        for (int ks = 0; ks < 2; ++ks) {
            bf8v bq[4];
#pragma unroll
            for (int j = 0; j < 4; ++j)
                bq[j] = *(const bf8v*)(Qb + (long long)(s0 + j * 16 + lq) * 1152
                                          + ks * 32 + quad * 8);
#pragma unroll
            for (int i = 0; i < 2; ++i)
#pragma unroll
                for (int j = 0; j < 4; ++j)
                    sacc[i][j] = __builtin_amdgcn_mfma_f32_16x16x32_bf16(af[i][ks], bq[j], sacc[i][j], 0, 0, 0);
        }
        // ---- scale + causal mask in place (C layout: row=quad*4+r, col=lq) ----
#pragma unroll
        for (int i = 0; i < 2; ++i)
#pragma unroll
            for (int j = 0; j < 4; ++j)
#pragma unroll
                for (int r = 0; r < 4; ++r) {
                    int t_g = t0 + wave * 32 + i * 16 + quad * 4 + r;
                    int s_g = s0 + j * 16 + lq;
                    float v = sacc[i][j][r] * scs;
                    sacc[i][j][r] = (s_g <= t_g) ? v : -1e30f;
                }
        // ---- online softmax update (per row (i,r); row spans j x lq) ----
#pragma unroll
        for (int i = 0; i < 2; ++i)
#pragma unroll
            for (int r = 0; r < 4; ++r) {
                float mt = sacc[i][0][r];
#pragma unroll
                for (int j = 1; j < 4; ++j) mt = fmaxf(mt, sacc[i][j][r]);
#pragma unroll
                for (int o = 8; o > 0; o >>= 1) mt = fmaxf(mt, __shfl_xor(mt, o));
                const float mn = fmaxf(m_run[i][r], mt);
                const float alpha = __expf(m_run[i][r] - mn);
                float rs = 0.f;
#pragma unroll
                for (int j = 0; j < 4; ++j) {
                    float e = __expf(sacc[i][j][r] - mn);
                    sacc[i][j][r] = e; rs += e;
                }
#pragma unroll
                for (int o = 8; o > 0; o >>= 1) rs += __shfl_xor(rs, o);
                m_run[i][r] = mn;
                l_run[i][r] = l_run[i][r] * alpha + rs;
#pragma unroll
                for (int j = 0; j < 4; ++j) oacc[i][j][r] *= alpha;
            }
        // ---- P tile to LDS (C layout -> A layout); wave-private rows, no barrier ----
#pragma unroll
        for (int i = 0; i < 2; ++i)
#pragma unroll
            for (int j = 0; j < 4; ++j)
#pragma unroll
                for (int r = 0; r < 4; ++r)
                    Pl[(wave * 32 + i * 16 + quad * 4 + r) * 72 + j * 16 + lq] = f2bf(sacc[i][j][r]);
        // ---- PV partial: out += P(32x64) @ V(64x64), B^T = Vt ----
#pragma unroll
        for (int ks2 = 0; ks2 < 2; ++ks2) {
            bf8v ap[2], bv_[4];
#pragma unroll
            for (int i = 0; i < 2; ++i)
                ap[i] = *(const bf8v*)(Pl + (wave * 32 + i * 16 + lq) * 72 + ks2 * 32 + quad * 8);
#pragma unroll
            for (int j = 0; j < 4; ++j)
                bv_[j] = *(const bf8v*)(Vtb + (long long)(j * 16 + lq) * 256 + s0 + ks2 * 32 + quad * 8);
#pragma unroll
            for (int i = 0; i < 2; ++i)
#pragma unroll
                for (int j = 0; j < 4; ++j)
                    oacc[i][j] = __builtin_amdgcn_mfma_f32_16x16x32_bf16(ap[i], bv_[j], oacc[i][j], 0, 0, 0);
        }
    }
    // ---- epilogue: normalize by l, scatter into (b,t,h*64+d) ----
#pragma unroll
    for (int i = 0; i < 2; ++i)
#pragma unroll
        for (int r = 0; r < 4; ++r) {
            const float inv = 1.f / l_run[i][r];
            u16* orow = attnout + ((long long)(b * TT + t0 + wave * 32 + i * 16 + quad * 4 + r)) * CC + hh * 64;
#pragma unroll
            for (int j = 0; j < 4; ++j)
                orow[j * 16 + lq] = f2bf(oacc[i][j][r] * inv);
        }
}

// ---------------- Generic bf16 MFMA GEMM: C = scale*(A @ B^T) [+bias][+res][relu]
// m97 structure: 128-wide tiles, BK=32, global_load_lds width-16 staging (R3-proven).
template<int BM, int BN, bool OUTBF, bool RELU, bool HASRES>
__global__ __launch_bounds__(256) void gemm_bt(
    const u16* __restrict__ A, const u16* __restrict__ Bw, void* __restrict__ Cp,
    const float* __restrict__ bias, const float* __restrict__ res,
    int K, int lda, int ldb, int ldc,
    long long sAb, long long sAh, long long sBb, long long sBh,
    long long sCb, long long sCh, int Hb, float scale)
{
    __shared__ __align__(16) u16 As[BM * 32];
    __shared__ __align__(16) u16 Bs[BN * 32];

    const int tid = threadIdx.x;
    const int wave = tid >> 6, lane = tid & 63;
    const int quad = lane >> 4, lq = lane & 15;

    const int z = blockIdx.z;
    const int zb = z / Hb, zh = z % Hb;
    const int m0 = blockIdx.x * BM;
    const int n0 = blockIdx.y * BN;

    A  += (long long)zb * sAb + (long long)zh * sAh + (long long)m0 * lda;
    Bw += (long long)zb * sBb + (long long)zh * sBh + (long long)n0 * ldb;
    const long long coff = (long long)zb * sCb + (long long)zh * sCh;

    constexpr int WM = BM / 2, WN = BN / 2;
    constexpr int MT = WM / 16, NT = WN / 16;
    const int wm0 = (wave >> 1) * WM;
    const int wn0 = (wave & 1) * WN;

    f4v acc[MT][NT];
#pragma unroll
    for (int i = 0; i < MT; ++i)
#pragma unroll
        for (int j = 0; j < NT; ++j) acc[i][j] = (f4v){0.f, 0.f, 0.f, 0.f};

    constexpr int AIT = BM / 64;
    constexpr int BIT = BN / 64;

    for (int k0 = 0; k0 < K; k0 += 32) {
        __syncthreads();
#pragma unroll
        for (int j = 0; j < AIT; ++j) {
            int idx = j * 256 + tid; int r = idx >> 2, c = idx & 3;
            gload_lds16(A + (long long)r * lda + k0 + c * 8, As + idx * 8);
        }
#pragma unroll
        for (int j = 0; j < BIT; ++j) {
            int idx = j * 256 + tid; int r = idx >> 2, c = idx & 3;
            gload_lds16(Bw + (long long)r * ldb + k0 + c * 8, Bs + idx * 8);
        }
        __syncthreads();

        bf8v af[MT], bfr[NT];
#pragma unroll
        for (int i = 0; i < MT; ++i)
            af[i] = *(const bf8v*)(As + (wm0 + i * 16 + lq) * 32 + quad * 8);
#pragma unroll
        for (int j = 0; j < NT; ++j)
            bfr[j] = *(const bf8v*)(Bs + (wn0 + j * 16 + lq) * 32 + quad * 8);
#pragma unroll
        for (int i = 0; i < MT; ++i)
#pragma unroll
            for (int j = 0; j < NT; ++j)
                acc[i][j] = __builtin_amdgcn_mfma_f32_16x16x32_bf16(af[i], bfr[j], acc[i][j], 0, 0, 0);
    }

#pragma unroll
    for (int i = 0; i < MT; ++i) {
#pragma unroll
        for (int j = 0; j < NT; ++j) {
            const int gcol = n0 + wn0 + j * 16 + lq;
            const float bcol = bias ? bias[gcol] : 0.f;
#pragma unroll
            for (int r = 0; r < 4; ++r) {
                const int grow = m0 + wm0 + i * 16 + quad * 4 + r;
                const long long off = coff + (long long)grow * ldc + gcol;
                float v = acc[i][j][r] * scale + bcol;
                if (HASRES) v += res[off];
                if (RELU)   v = fmaxf(v, 0.f);
                if (OUTBF)  ((u16*)Cp)[off] = f2bf(v);
                else        ((float*)Cp)[off] = v;
            }
        }
    }
}

extern "C" void kernel_launch(void* const* d_in, const int* in_sizes, int n_in,
                              void* d_out, int out_size, void* d_ws, size_t ws_size,
                              hipStream_t stream)
{
    const float* x    = (const float*)d_in[0];
    const float* ln1g = (const float*)d_in[1];
    const float* ln1b = (const float*)d_in[2];
    const float* Wk   = (const float*)d_in[3];
    const float* bk   = (const float*)d_in[4];
    const float* Wq   = (const float*)d_in[5];
    const float* bq   = (const float*)d_in[6];
    const float* Wv   = (const float*)d_in[7];
    const float* bv   = (const float*)d_in[8];
    const float* Wp   = (const float*)d_in[9];
    const float* bp   = (const float*)d_in[10];
    const float* ln2g = (const float*)d_in[11];
    const float* ln2b = (const float*)d_in[12];
    const float* W1   = (const float*)d_in[13];
    const float* b1   = (const float*)d_in[14];
    const float* W2   = (const float*)d_in[15];
    const float* b2   = (const float*)d_in[16];

    // ---- workspace carve-up: peak ~154.5 MB (R3-proven) ----
    char* ws = (char*)d_ws;
    size_t off = 0;
    auto alloc = [&](size_t bytes) -> char* {
        char* p = ws + off; off += (bytes + 255) & ~(size_t)255; return p;
    };
    u16*   wqkvT = (u16*)alloc((size_t)1152 * 384 * 2);
    u16*   wpT   = (u16*)alloc((size_t)384 * 384 * 2);
    u16*   w1T   = (u16*)alloc((size_t)1536 * 384 * 2);
    u16*   w2T   = (u16*)alloc((size_t)384 * 1536 * 2);
    float* bqkv  = (float*)alloc((size_t)1152 * 4);
    u16*   h     = (u16*)alloc((size_t)ROWS * CC * 2);             // LN1 out; reused: attnout, h2
    u16*   qkv   = (u16*)alloc((size_t)ROWS * 1152 * 2);           // Q|K|V; reused: x1 (fp32)
    u16*   vtff  = (u16*)alloc((size_t)FCH * FFF * 2);             // vt (25.2MB) then ff (50.3MB)
    u16* attnout = h;
    u16* h2      = h;
    float* x1    = (float*)qkv;   // 50.3 MB inside dead 75.5 MB qkv region
    u16*   vt    = vtff;
    u16*   ff    = vtff;

    // 1) LN1
    ln_kernel<<<ROWS / 4, 256, 0, stream>>>(x, ln1g, ln1b, h);
    // 2) weight convert/transpose/pack
    cvt_weights<<<6918, 256, 0, stream>>>(Wq, Wk, Wv, bq, bk, bv, Wp, W1, W2,
                                          wqkvT, wpT, w1T, w2T, bqkv);
    // 3) QKV
    gemm_bt<128, 128, true, false, false><<<dim3(ROWS / 128, 1152 / 128, 1), 256, 0, stream>>>(
        h, wqkvT, qkv, bqkv, nullptr, 384, 384, 384, 1152,
        0, 0, 0, 0, 0, 0, 1, 1.f);
    // 4) V transpose
    vtrans_kernel<<<dim3(BB * HH, 4), 256, 0, stream>>>(qkv, vt);
    // 5) fused flash attention (replaces scores GEMM + softmax + PV GEMM + sc buffer)
    flash_kernel<<<dim3(BB * HH, 2), 256, 0, stream>>>(qkv, vt, attnout);
    // 6) x1 = x + attnout @ Wp + bp   (x1 aliases dead qkv)
    gemm_bt<128, 128, false, false, true><<<dim3(ROWS / 128, CC / 128, 1), 256, 0, stream>>>(
        attnout, wpT, x1, bp, x, CC, CC, CC, CC,
        0, 0, 0, 0, 0, 0, 1, 1.f);
    // 7) LN2
    ln_kernel<<<ROWS / 4, 256, 0, stream>>>(x1, ln2g, ln2b, h2);
    // 8-9) FFN, chunked over rows (ff aliases dead vt)
    for (int fc = 0; fc < NFC; ++fc) {
        const long long ro = (long long)fc * FCH;
        gemm_bt<128, 128, true, true, false><<<dim3(FCH / 128, FFF / 128, 1), 256, 0, stream>>>(
            h2 + ro * CC, w1T, ff, b1, nullptr, CC, CC, CC, FFF,
            0, 0, 0, 0, 0, 0, 1, 1.f);
        gemm_bt<128, 128, false, false, true><<<dim3(FCH / 128, CC / 128, 1), 256, 0, stream>>>(
            ff, w2T, (float*)d_out + ro * CC, b2, x1 + ro * CC, FFF, FFF, FFF, CC,
            0, 0, 0, 0, 0, 0, 1, 1.f);
    }
}